// Round 2
// 486.090 us; speedup vs baseline: 1.1302x; 1.1302x over previous
//
#include <hip/hip_runtime.h>

#define NB 16
#define CIN 768
#define HC 8
#define LT 4160
#define LOG2E 1.44269504088896f

// ---------------------------------------------------------------------------
// K1: x(B,LT,768) fp32 @ W(768,8) + b -> out(B,Lseg,8), both segments merged.
// one wave per 16 rows; W preloaded into 96 regs/lane (c = lane*4 + j + 256k)
// x row loads vectorized to float4 (3 x dwordx4 per row per lane).
// Row reduce: butterfly{1,2,4} -> cndmask-select -> butterfly{8,16,32},
// lanes 0..7 store 8 contiguous floats.
// ---------------------------------------------------------------------------
__global__ __launch_bounds__(256) void proj_kernel(
    const float* __restrict__ x,
    const float* __restrict__ W00, const float* __restrict__ b00,
    const float* __restrict__ W01, const float* __restrict__ b01,
    float* __restrict__ x0t, float* __restrict__ x1t)
{
  const int tid  = threadIdx.x;
  const int lane = tid & 63;
  const int wid  = tid >> 6;
  const int b    = blockIdx.y;
  int bx = blockIdx.x;

  const float* W; const float* bias; float* out; int segoff, Lseg;
  if (bx < 16) { W = W00; bias = b00; out = x0t; segoff = 0;    Lseg = 1024; }
  else { bx -= 16; W = W01; bias = b01; out = x1t; segoff = 1024; Lseg = 3136; }

  float wreg[3][4][8];
#pragma unroll
  for (int k = 0; k < 3; ++k) {
#pragma unroll
    for (int j = 0; j < 4; ++j) {
      const int c = lane * 4 + j + 256 * k;
      const float4 a  = *reinterpret_cast<const float4*>(W + (size_t)c * 8);
      const float4 d4 = *reinterpret_cast<const float4*>(W + (size_t)c * 8 + 4);
      wreg[k][j][0]=a.x;  wreg[k][j][1]=a.y;  wreg[k][j][2]=a.z;  wreg[k][j][3]=a.w;
      wreg[k][j][4]=d4.x; wreg[k][j][5]=d4.y; wreg[k][j][6]=d4.z; wreg[k][j][7]=d4.w;
    }
  }
  const float bv = (lane < 8) ? bias[lane] : 0.f;

  const int l0 = bx * 64 + wid * 16;
  const float* xb = x + ((size_t)b * LT + segoff) * CIN;
  float* ob = out + (size_t)b * Lseg * HC;

  for (int r = 0; r < 16; ++r) {
    const int l = l0 + r;
    const float* xr = xb + (size_t)l * CIN;
    float acc[8] = {0.f,0.f,0.f,0.f,0.f,0.f,0.f,0.f};
#pragma unroll
    for (int k = 0; k < 3; ++k) {
      const float4 xv = *reinterpret_cast<const float4*>(xr + lane * 4 + 256 * k);
      const float xs[4] = {xv.x, xv.y, xv.z, xv.w};
#pragma unroll
      for (int j = 0; j < 4; ++j)
#pragma unroll
        for (int d = 0; d < 8; ++d) acc[d] = fmaf(xs[j], wreg[k][j][d], acc[d]);
    }
    // stage 1: allreduce within 8-lane subgroups
#pragma unroll
    for (int off = 1; off < 8; off <<= 1)
#pragma unroll
      for (int d = 0; d < 8; ++d) acc[d] += __shfl_xor(acc[d], off, 64);
    // select own d, then reduce across subgroups
    const int d7 = lane & 7;
    float v = acc[0];
#pragma unroll
    for (int d = 1; d < 8; ++d) v = (d7 == d) ? acc[d] : v;
#pragma unroll
    for (int off = 8; off < 64; off <<= 1) v += __shfl_xor(v, off, 64);
    if (lane < 8) ob[(size_t)l * HC + lane] = v + bv;
  }
}

// ---------------------------------------------------------------------------
// K2: both flash attentions in one launch, D=8, single pass, no max tracking
// (scores |s| <~ 17 -> exp(s) safe in fp32; softmax identical without max-sub).
// block = 512 thr (8 waves), wave owns 4 query rows, lanes split over j.
// Q pre-scaled by log2e so p = exp2(dot) = exp(raw score).
// K chunked 1024 rows -> LDS transposed [d][j].
// ---------------------------------------------------------------------------
__global__ __launch_bounds__(512) void attn_kernel(
    const float* __restrict__ x0t, const float* __restrict__ x1t,
    float* __restrict__ x0_1, float* __restrict__ x1_0)
{
  __shared__ float kvs[8 * 1024]; // 32 KB, [d][j]
  const int tid  = threadIdx.x;
  const int lane = tid & 63;
  const int wid  = tid >> 6;
  const int b    = blockIdx.y;
  int bx = blockIdx.x;

  const float *Q, *K; float* O; int Lq, Lk;
  if (bx < 32) { Q = x0t; K = x1t; O = x0_1; Lq = 1024; Lk = 3136; }
  else { bx -= 32; Q = x1t; K = x0t; O = x1_0; Lq = 3136; Lk = 1024; }

  const int q0 = bx * 32 + wid * 4;
  const float* Qb = Q + ((size_t)b * Lq + q0) * HC;
  float q[4][8];
#pragma unroll
  for (int r = 0; r < 4; ++r) {
    const float4 a = *reinterpret_cast<const float4*>(Qb + r * 8);
    const float4 c = *reinterpret_cast<const float4*>(Qb + r * 8 + 4);
    q[r][0]=a.x*LOG2E; q[r][1]=a.y*LOG2E; q[r][2]=a.z*LOG2E; q[r][3]=a.w*LOG2E;
    q[r][4]=c.x*LOG2E; q[r][5]=c.y*LOG2E; q[r][6]=c.z*LOG2E; q[r][7]=c.w*LOG2E;
  }
  float sum[4] = {0.f,0.f,0.f,0.f};
  float acc[4][8];
#pragma unroll
  for (int r = 0; r < 4; ++r)
#pragma unroll
    for (int d = 0; d < 8; ++d) acc[r][d] = 0.f;

  const float* Kb = K + (size_t)b * Lk * HC;

  for (int c0 = 0; c0 < Lk; c0 += 1024) {
    const int clen = min(1024, Lk - c0);
    __syncthreads();
    for (int j = tid; j < clen; j += 512) {
      const float* kr = Kb + (size_t)(c0 + j) * HC;
      const float4 a = *reinterpret_cast<const float4*>(kr);
      const float4 c = *reinterpret_cast<const float4*>(kr + 4);
      kvs[0*1024+j]=a.x; kvs[1*1024+j]=a.y; kvs[2*1024+j]=a.z; kvs[3*1024+j]=a.w;
      kvs[4*1024+j]=c.x; kvs[5*1024+j]=c.y; kvs[6*1024+j]=c.z; kvs[7*1024+j]=c.w;
    }
    __syncthreads();
    const int iters = clen >> 6;
#pragma unroll 2
    for (int it = 0; it < iters; ++it) {
      const int j = it * 64 + lane;
      float kx[8];
#pragma unroll
      for (int d = 0; d < 8; ++d) kx[d] = kvs[d * 1024 + j];
#pragma unroll
      for (int r = 0; r < 4; ++r) {
        float s = 0.f;
#pragma unroll
        for (int d = 0; d < 8; ++d) s = fmaf(q[r][d], kx[d], s);
        const float p = exp2f(s); // = exp(raw_score)
        sum[r] += p;
#pragma unroll
        for (int d = 0; d < 8; ++d) acc[r][d] = fmaf(p, kx[d], acc[r][d]);
      }
    }
  }

  // endgame: per row, butterfly{1,2,4} -> select -> butterfly{8,16,32}
  const int d7 = lane & 7;
#pragma unroll
  for (int r = 0; r < 4; ++r) {
    float s = sum[r];
#pragma unroll
    for (int off = 1; off < 8; off <<= 1) {
      s += __shfl_xor(s, off, 64);
#pragma unroll
      for (int d = 0; d < 8; ++d) acc[r][d] += __shfl_xor(acc[r][d], off, 64);
    }
    float v = acc[r][0];
#pragma unroll
    for (int d = 1; d < 8; ++d) v = (d7 == d) ? acc[r][d] : v;
#pragma unroll
    for (int off = 8; off < 64; off <<= 1) {
      v += __shfl_xor(v, off, 64);
      s += __shfl_xor(s, off, 64);
    }
    if (lane < 8)
      O[((size_t)b * Lq + q0 + r) * HC + lane] = __fdividef(v, s);
  }
}

// ---------------------------------------------------------------------------
// K3: fovea for both tensors in one launch. Column cached in LDS: T read once.
// No max-subtraction (|t| small; exp fp32-safe). one block per (tensor,b,d).
// ---------------------------------------------------------------------------
__global__ __launch_bounds__(256) void fovea_kernel(
    const float* __restrict__ x0t, const float* __restrict__ x0_1, float* __restrict__ x0o,
    const float* __restrict__ x1_0, const float* __restrict__ x1t, float* __restrict__ x1o)
{
  __shared__ float tv[3136];
  __shared__ float reds[4];
  int bid = blockIdx.x;
  const float *T, *A; float* O; int L;
  if (bid < 128) { T = x0t; A = x0_1; O = x0o; L = 1024; }
  else { bid -= 128; T = x1_0; A = x1t; O = x1o; L = 3136; }

  const int tid  = threadIdx.x;
  const int lane = tid & 63;
  const int wid  = tid >> 6;
  const int b = bid >> 3;
  const int d = bid & 7;
  const float* t = T + (size_t)b * L * HC + d;
  const float* a = A + (size_t)b * L * HC + d;
  float* o = O + (size_t)b * L * HC + d;

  float s = 0.f;
  for (int l = tid; l < L; l += 256) {
    const float v = t[(size_t)l * HC];
    tv[l] = v;
    s += __expf(v);
  }
#pragma unroll
  for (int off = 32; off > 0; off >>= 1) s += __shfl_xor(s, off, 64);
  if (lane == 0) reds[wid] = s;
  __syncthreads();
  const float inv = 1.f / (reds[0] + reds[1] + reds[2] + reds[3]);

  for (int l = tid; l < L; l += 256) {
    const float v = tv[l];
    o[(size_t)l * HC] = __expf(v) * inv * v + a[(size_t)l * HC];
  }
}

// ---------------------------------------------------------------------------
// K4: both output projections in one launch.
// XO(B,L,8) @ W(8,768) + b -> out(B,768,L) fp32 (transposed write)
// block (64,4): tx along l (coalesced stores), each thread owns 4 c values
// ---------------------------------------------------------------------------
__global__ __launch_bounds__(256) void outproj_kernel(
    const float* __restrict__ x0o, const float* __restrict__ W1, const float* __restrict__ b1,
    const float* __restrict__ x1o, const float* __restrict__ W2, const float* __restrict__ b2,
    float* __restrict__ out)
{
  const int tx = threadIdx.x;
  const int ty = threadIdx.y;
  const int b  = blockIdx.z;
  const int c0 = blockIdx.y * 16;
  int bx = blockIdx.x;

  const float *XO, *W, *bias; float* ob; int L, nj;
  if (bx < 4) { XO = x0o; W = W1; bias = b1; ob = out; L = 1024; nj = 4; }
  else { bx -= 4; XO = x1o; W = W2; bias = b2;
         ob = out + (size_t)NB * CIN * 1024; L = 3136; nj = 7; }

  const int l0 = bx * (nj * 64);

  float w[4][8], bv[4];
#pragma unroll
  for (int k = 0; k < 4; ++k) {
    const int c = c0 + ty * 4 + k;
#pragma unroll
    for (int d = 0; d < 8; ++d) w[k][d] = W[d * CIN + c];
    bv[k] = bias[c];
  }

  for (int j = 0; j < nj; ++j) {
    const int l = l0 + j * 64 + tx;
    const float* xr = XO + ((size_t)b * L + l) * HC;
    const float4 a  = *reinterpret_cast<const float4*>(xr);
    const float4 c4 = *reinterpret_cast<const float4*>(xr + 4);
    const float qv[8] = {a.x, a.y, a.z, a.w, c4.x, c4.y, c4.z, c4.w};
#pragma unroll
    for (int k = 0; k < 4; ++k) {
      float acc = bv[k];
#pragma unroll
      for (int d = 0; d < 8; ++d) acc = fmaf(qv[d], w[k][d], acc);
      ob[((size_t)b * CIN + (c0 + ty * 4 + k)) * L + l] = acc;
    }
  }
}

// ---------------------------------------------------------------------------
extern "C" void kernel_launch(void* const* d_in, const int* in_sizes, int n_in,
                              void* d_out, int out_size, void* d_ws, size_t ws_size,
                              hipStream_t stream)
{
  const float* x   = (const float*)d_in[0];
  const float* W00 = (const float*)d_in[1];
  const float* b00 = (const float*)d_in[2];
  const float* W01 = (const float*)d_in[3];
  const float* b01 = (const float*)d_in[4];
  const float* W1  = (const float*)d_in[5];
  const float* b1  = (const float*)d_in[6];
  const float* W2  = (const float*)d_in[7];
  const float* b2  = (const float*)d_in[8];
  float* out = (float*)d_out;

  float* ws   = (float*)d_ws;
  float* x0t  = ws;                        // 16*1024*8
  float* x1t  = x0t  + (size_t)16*1024*8;  // 16*3136*8
  float* x0_1 = x1t  + (size_t)16*3136*8;
  float* x1_0 = x0_1 + (size_t)16*1024*8;
  float* x0o  = x1_0 + (size_t)16*3136*8;
  float* x1o  = x0o  + (size_t)16*1024*8;  // total 6.4 MB

  proj_kernel<<<dim3(65, 16), 256, 0, stream>>>(x, W00, b00, W01, b01, x0t, x1t);
  attn_kernel<<<dim3(130, 16), 512, 0, stream>>>(x0t, x1t, x0_1, x1_0);
  fovea_kernel<<<256, 256, 0, stream>>>(x0t, x0_1, x0o, x1_0, x1t, x1o);
  outproj_kernel<<<dim3(11, 48, 16), dim3(64, 4), 0, stream>>>(
      x0o, W1, b1, x1o, W2, b2, out);
}

// Round 3
// 470.184 us; speedup vs baseline: 1.1684x; 1.0338x over previous
//
#include <hip/hip_runtime.h>

#define NB 16
#define CIN 768
#define HC 8
#define LT 4160
#define LOG2E 1.44269504088896f

// ---------------------------------------------------------------------------
// K1: x(B,LT,768) fp32 @ W(768,8) + b -> out(B,Lseg,8), both segments merged.
// one wave per 16 rows; W preloaded into 96 regs/lane (c = lane*4 + j + 256k).
// Next-row prefetch keeps 3 dwordx4 loads in flight across the reduce endgame.
// seg0 blocks also accumulate S0[b,d] = sum_l exp(x0t[b,l,d]) (fovea denom).
// ---------------------------------------------------------------------------
__global__ __launch_bounds__(256) void proj_kernel(
    const float* __restrict__ x,
    const float* __restrict__ W00, const float* __restrict__ b00,
    const float* __restrict__ W01, const float* __restrict__ b01,
    float* __restrict__ x0t, float* __restrict__ x1t,
    float* __restrict__ S0)
{
  __shared__ float pred[4][8];
  const int tid  = threadIdx.x;
  const int lane = tid & 63;
  const int wid  = tid >> 6;
  const int b    = blockIdx.y;
  int bx = blockIdx.x;

  const bool seg0 = (bx < 16);
  const float* W; const float* bias; float* out; int segoff, Lseg;
  if (seg0) { W = W00; bias = b00; out = x0t; segoff = 0;    Lseg = 1024; }
  else { bx -= 16; W = W01; bias = b01; out = x1t; segoff = 1024; Lseg = 3136; }

  float wreg[3][4][8];
#pragma unroll
  for (int k = 0; k < 3; ++k) {
#pragma unroll
    for (int j = 0; j < 4; ++j) {
      const int c = lane * 4 + j + 256 * k;
      const float4 a  = *reinterpret_cast<const float4*>(W + (size_t)c * 8);
      const float4 d4 = *reinterpret_cast<const float4*>(W + (size_t)c * 8 + 4);
      wreg[k][j][0]=a.x;  wreg[k][j][1]=a.y;  wreg[k][j][2]=a.z;  wreg[k][j][3]=a.w;
      wreg[k][j][4]=d4.x; wreg[k][j][5]=d4.y; wreg[k][j][6]=d4.z; wreg[k][j][7]=d4.w;
    }
  }
  const float bv = (lane < 8) ? bias[lane] : 0.f;

  const int l0 = bx * 64 + wid * 16;
  const float* xb = x + ((size_t)b * LT + segoff) * CIN;
  float* ob = out + (size_t)b * Lseg * HC;

  float4 xv[3];
#pragma unroll
  for (int k = 0; k < 3; ++k)
    xv[k] = *reinterpret_cast<const float4*>(xb + (size_t)l0 * CIN + lane * 4 + 256 * k);

  float es = 0.f;
  for (int r = 0; r < 16; ++r) {
    const int l = l0 + r;
    const float4 cur[3] = {xv[0], xv[1], xv[2]};
    if (r < 15) {
      const float* xr = xb + (size_t)(l + 1) * CIN;
#pragma unroll
      for (int k = 0; k < 3; ++k)
        xv[k] = *reinterpret_cast<const float4*>(xr + lane * 4 + 256 * k);
    }
    float acc[8] = {0.f,0.f,0.f,0.f,0.f,0.f,0.f,0.f};
#pragma unroll
    for (int k = 0; k < 3; ++k) {
      const float xs[4] = {cur[k].x, cur[k].y, cur[k].z, cur[k].w};
#pragma unroll
      for (int j = 0; j < 4; ++j)
#pragma unroll
        for (int d = 0; d < 8; ++d) acc[d] = fmaf(xs[j], wreg[k][j][d], acc[d]);
    }
    // stage 1: allreduce within 8-lane subgroups
#pragma unroll
    for (int off = 1; off < 8; off <<= 1)
#pragma unroll
      for (int d = 0; d < 8; ++d) acc[d] += __shfl_xor(acc[d], off, 64);
    // select own d, then reduce across subgroups
    const int d7 = lane & 7;
    float v = acc[0];
#pragma unroll
    for (int d = 1; d < 8; ++d) v = (d7 == d) ? acc[d] : v;
#pragma unroll
    for (int off = 8; off < 64; off <<= 1) v += __shfl_xor(v, off, 64);
    if (lane < 8) {
      const float val = v + bv;
      ob[(size_t)l * HC + lane] = val;
      if (seg0) es += __expf(val);
    }
  }

  if (seg0) {
    if (lane < 8) pred[wid][lane] = es;
    __syncthreads();
    if (tid < 8)
      atomicAdd(&S0[(size_t)b * 8 + tid],
                pred[0][tid] + pred[1][tid] + pred[2][tid] + pred[3][tid]);
  }
}

// ---------------------------------------------------------------------------
// K2: both flash attentions in one launch, D=8, single pass, no max tracking
// (scores |s| <~ 17 -> exp(s) safe in fp32; softmax identical without max-sub).
// No LDS staging: K side is L2-resident (<=2.1 MB); each lane reads one K row
// as 2 float4 (wave = one contiguous 2KB dwordx4). Register double-buffered
// prefetch of the next iteration's K row. 256-thr blocks, no barriers in loop.
// attn2 blocks accumulate S1[b,d] = sum_l exp(x1_0[b,l,d]) (fovea denom).
// ---------------------------------------------------------------------------
__global__ __launch_bounds__(256) void attn_kernel(
    const float* __restrict__ x0t, const float* __restrict__ x1t,
    float* __restrict__ x0_1, float* __restrict__ x1_0,
    float* __restrict__ S1)
{
  __shared__ float sred[4][8];
  const int tid  = threadIdx.x;
  const int lane = tid & 63;
  const int wid  = tid >> 6;
  const int b    = blockIdx.y;
  int bx = blockIdx.x;

  const float *Q, *K; float* O; int Lq, Lk; bool a2;
  if (bx < 64) { Q = x0t; K = x1t; O = x0_1; Lq = 1024; Lk = 3136; a2 = false; }
  else { bx -= 64; Q = x1t; K = x0t; O = x1_0; Lq = 3136; Lk = 1024; a2 = true; }

  const int q0 = bx * 16 + wid * 4;
  const float* Qb = Q + ((size_t)b * Lq + q0) * HC;
  float q[4][8];
#pragma unroll
  for (int r = 0; r < 4; ++r) {
    const float4 a = *reinterpret_cast<const float4*>(Qb + r * 8);
    const float4 c = *reinterpret_cast<const float4*>(Qb + r * 8 + 4);
    q[r][0]=a.x*LOG2E; q[r][1]=a.y*LOG2E; q[r][2]=a.z*LOG2E; q[r][3]=a.w*LOG2E;
    q[r][4]=c.x*LOG2E; q[r][5]=c.y*LOG2E; q[r][6]=c.z*LOG2E; q[r][7]=c.w*LOG2E;
  }
  float sum[4] = {0.f,0.f,0.f,0.f};
  float acc[4][8];
#pragma unroll
  for (int r = 0; r < 4; ++r)
#pragma unroll
    for (int d = 0; d < 8; ++d) acc[r][d] = 0.f;

  const float* Kb = K + (size_t)b * Lk * HC;
  const int iters = Lk >> 6; // Lk is a multiple of 64

  float4 pa = *reinterpret_cast<const float4*>(Kb + (size_t)lane * 8);
  float4 pc = *reinterpret_cast<const float4*>(Kb + (size_t)lane * 8 + 4);

  for (int it = 0; it < iters; ++it) {
    const float kx[8] = {pa.x, pa.y, pa.z, pa.w, pc.x, pc.y, pc.z, pc.w};
    if (it + 1 < iters) {
      const float* kr = Kb + (size_t)((it + 1) * 64 + lane) * 8;
      pa = *reinterpret_cast<const float4*>(kr);
      pc = *reinterpret_cast<const float4*>(kr + 4);
    }
#pragma unroll
    for (int r = 0; r < 4; ++r) {
      float s = 0.f;
#pragma unroll
      for (int d = 0; d < 8; ++d) s = fmaf(q[r][d], kx[d], s);
      const float p = exp2f(s); // = exp(raw_score)
      sum[r] += p;
#pragma unroll
      for (int d = 0; d < 8; ++d) acc[r][d] = fmaf(p, kx[d], acc[r][d]);
    }
  }

  // endgame: per row, butterfly{1,2,4} -> select -> butterfly{8,16,32}
  const int d7 = lane & 7;
  float es = 0.f;
#pragma unroll
  for (int r = 0; r < 4; ++r) {
    float s = sum[r];
#pragma unroll
    for (int off = 1; off < 8; off <<= 1) {
      s += __shfl_xor(s, off, 64);
#pragma unroll
      for (int d = 0; d < 8; ++d) acc[r][d] += __shfl_xor(acc[r][d], off, 64);
    }
    float v = acc[r][0];
#pragma unroll
    for (int d = 1; d < 8; ++d) v = (d7 == d) ? acc[r][d] : v;
#pragma unroll
    for (int off = 8; off < 64; off <<= 1) {
      v += __shfl_xor(v, off, 64);
      s += __shfl_xor(s, off, 64);
    }
    if (lane < 8) {
      const float val = __fdividef(v, s);
      O[((size_t)b * Lq + q0 + r) * HC + lane] = val;
      if (a2) es += __expf(val);
    }
  }

  if (a2) {
    if (lane < 8) sred[wid][lane] = es;
    __syncthreads();
    if (tid < 8)
      atomicAdd(&S1[(size_t)b * 8 + tid],
                sred[0][tid] + sred[1][tid] + sred[2][tid] + sred[3][tid]);
  }
}

// ---------------------------------------------------------------------------
// K3: fovea, now single-pass elementwise (denominators precomputed in K1/K2).
// o[l,d] = exp(t[l,d]) / S[b,d] * t[l,d] + a[l,d]. float4 in/out, coalesced.
// ---------------------------------------------------------------------------
__global__ __launch_bounds__(256) void fovea_kernel(
    const float* __restrict__ x0t, const float* __restrict__ x0_1, float* __restrict__ x0o,
    const float* __restrict__ x1_0, const float* __restrict__ x1t, float* __restrict__ x1o,
    const float* __restrict__ S0, const float* __restrict__ S1)
{
  const int b = blockIdx.y;
  int bx = blockIdx.x;
  const float *T, *A, *S; float* O; int L;
  if (bx < 4) { T = x0t; A = x0_1; O = x0o; S = S0; L = 1024; }
  else { bx -= 4; T = x1_0; A = x1t; O = x1o; S = S1; L = 3136; }

  const int l = bx * 256 + threadIdx.x;
  if (l >= L) return;

  float inv[8];
#pragma unroll
  for (int d = 0; d < 8; ++d) inv[d] = 1.f / S[(size_t)b * 8 + d];

  const size_t base = ((size_t)b * L + l) * HC;
  const float4 ta = *reinterpret_cast<const float4*>(T + base);
  const float4 tc = *reinterpret_cast<const float4*>(T + base + 4);
  const float4 aa = *reinterpret_cast<const float4*>(A + base);
  const float4 ac = *reinterpret_cast<const float4*>(A + base + 4);
  float4 oa, oc;
  oa.x = __expf(ta.x) * inv[0] * ta.x + aa.x;
  oa.y = __expf(ta.y) * inv[1] * ta.y + aa.y;
  oa.z = __expf(ta.z) * inv[2] * ta.z + aa.z;
  oa.w = __expf(ta.w) * inv[3] * ta.w + aa.w;
  oc.x = __expf(tc.x) * inv[4] * tc.x + ac.x;
  oc.y = __expf(tc.y) * inv[5] * tc.y + ac.y;
  oc.z = __expf(tc.z) * inv[6] * tc.z + ac.z;
  oc.w = __expf(tc.w) * inv[7] * tc.w + ac.w;
  *reinterpret_cast<float4*>(O + base)     = oa;
  *reinterpret_cast<float4*>(O + base + 4) = oc;
}

// ---------------------------------------------------------------------------
// K4: both output projections in one launch.
// XO(B,L,8) @ W(8,768) + b -> out(B,768,L) fp32 (transposed write)
// block (64,4): tx along l (coalesced stores), each thread owns 4 c values.
// Next-row prefetch of the XO row.
// ---------------------------------------------------------------------------
__global__ __launch_bounds__(256) void outproj_kernel(
    const float* __restrict__ x0o, const float* __restrict__ W1, const float* __restrict__ b1,
    const float* __restrict__ x1o, const float* __restrict__ W2, const float* __restrict__ b2,
    float* __restrict__ out)
{
  const int tx = threadIdx.x;
  const int ty = threadIdx.y;
  const int b  = blockIdx.z;
  const int c0 = blockIdx.y * 16;
  int bx = blockIdx.x;

  const float *XO, *W, *bias; float* ob; int L, nj;
  if (bx < 4) { XO = x0o; W = W1; bias = b1; ob = out; L = 1024; nj = 4; }
  else { bx -= 4; XO = x1o; W = W2; bias = b2;
         ob = out + (size_t)NB * CIN * 1024; L = 3136; nj = 7; }

  const int l0 = bx * (nj * 64);

  float w[4][8], bv[4];
#pragma unroll
  for (int k = 0; k < 4; ++k) {
    const int c = c0 + ty * 4 + k;
#pragma unroll
    for (int d = 0; d < 8; ++d) w[k][d] = W[d * CIN + c];
    bv[k] = bias[c];
  }

  const float* xr0 = XO + ((size_t)b * L + l0 + tx) * HC;
  float4 a  = *reinterpret_cast<const float4*>(xr0);
  float4 c4 = *reinterpret_cast<const float4*>(xr0 + 4);

  for (int j = 0; j < nj; ++j) {
    const int l = l0 + j * 64 + tx;
    const float qv[8] = {a.x, a.y, a.z, a.w, c4.x, c4.y, c4.z, c4.w};
    if (j + 1 < nj) {
      const float* xr = XO + ((size_t)b * L + l + 64) * HC;
      a  = *reinterpret_cast<const float4*>(xr);
      c4 = *reinterpret_cast<const float4*>(xr + 4);
    }
#pragma unroll
    for (int k = 0; k < 4; ++k) {
      float acc = bv[k];
#pragma unroll
      for (int d = 0; d < 8; ++d) acc = fmaf(qv[d], w[k][d], acc);
      ob[((size_t)b * CIN + (c0 + ty * 4 + k)) * L + l] = acc;
    }
  }
}

// ---------------------------------------------------------------------------
extern "C" void kernel_launch(void* const* d_in, const int* in_sizes, int n_in,
                              void* d_out, int out_size, void* d_ws, size_t ws_size,
                              hipStream_t stream)
{
  const float* x   = (const float*)d_in[0];
  const float* W00 = (const float*)d_in[1];
  const float* b00 = (const float*)d_in[2];
  const float* W01 = (const float*)d_in[3];
  const float* b01 = (const float*)d_in[4];
  const float* W1  = (const float*)d_in[5];
  const float* b1  = (const float*)d_in[6];
  const float* W2  = (const float*)d_in[7];
  const float* b2  = (const float*)d_in[8];
  float* out = (float*)d_out;

  float* ws   = (float*)d_ws;
  float* x0t  = ws;                        // 16*1024*8
  float* x1t  = x0t  + (size_t)16*1024*8;  // 16*3136*8
  float* x0_1 = x1t  + (size_t)16*3136*8;
  float* x1_0 = x0_1 + (size_t)16*1024*8;
  float* x0o  = x1_0 + (size_t)16*3136*8;
  float* x1o  = x0o  + (size_t)16*1024*8;
  float* S0   = x1o  + (size_t)16*3136*8;  // 16*8 floats
  float* S1   = S0 + 128;                  // 16*8 floats

  hipMemsetAsync(S0, 0, 256 * sizeof(float), stream);

  proj_kernel<<<dim3(65, 16), 256, 0, stream>>>(
      x, W00, b00, W01, b01, x0t, x1t, S0);
  attn_kernel<<<dim3(260, 16), 256, 0, stream>>>(
      x0t, x1t, x0_1, x1_0, S1);
  fovea_kernel<<<dim3(17, 16), 256, 0, stream>>>(
      x0t, x0_1, x0o, x1_0, x1t, x1o, S0, S1);
  outproj_kernel<<<dim3(11, 48, 16), dim3(64, 4), 0, stream>>>(
      x0o, W1, b1, x1o, W2, b2, out);
}